// Round 13
// baseline (96.131 us; speedup 1.0000x reference)
//
#include <hip/hip_runtime.h>
#include <hip/hip_bf16.h>

#define B_   32
#define N_   128
#define AH_  512
#define AW_  512
#define LCAP 64    // per-chunk list capacity (one 64-box ballot chunk)
#define LN2  0.6931471805599453f

// compiler-only reordering fence; one wave's DS ops execute in issue order
#define CFENCE() asm volatile("" ::: "memory")

// ---------------------------------------------------------------------------
// R13 = R6 body VERBATIM (att loads first -- every att-first variant hit
// 29.4, every bbox-first variant 35+), plus three off-path changes:
//  1. fused tail: last-block pattern (block_sums + counter + threadfence);
//     the final reduce runs in fixed index order -> bit-deterministic.
//  2. log2-domain BCE (__log2f, one ln2 scale in the finalize) -- drops the
//     per-log v_mul the compiler emits for __logf.
//  3. raster span bounds via readfirstlane -> SALU loop control.
// ---------------------------------------------------------------------------
__global__ __launch_bounds__(128) void row_bce_kernel(
    const float* __restrict__ att,
    const float* __restrict__ bboxs,
    const int*   __restrict__ img_h_p,
    const int*   __restrict__ img_w_p,
    float*       __restrict__ block_sums,   // [4096]
    unsigned*    __restrict__ counter,      // zeroed per launch
    float*       __restrict__ out)
{
    const int t    = threadIdx.x;
    const int lane = t & 63;
    const int wid  = t >> 6;                    // 0..1
    const int task = (blockIdx.x << 1) | wid;   // 0..8191
    const int b    = task >> 8;                 // 256 tasks per image
    const int y0   = (task & 255) << 1;         // rows y0, y0+1

    __shared__ float4 s_geo[2][LCAP];           // {pack(x1,x2,ab), x1m, x2m, -}
    __shared__ float2 s_rv [2][LCAP];           // {rowv0, rowv1}
    __shared__ float  s_mask[2][2][AW_];        // [wid][row][x]
    __shared__ float  s_bsum[2];
    __shared__ int    s_last;

    // ---- att loads FIRST (proven: att-first = 29.4, bbox-first = 35+) ----
    const float4* p4 = (const float4*)(att + ((size_t)b * AH_ + y0) * AW_);
    float4 P[2][2];
    #pragma unroll
    for (int r = 0; r < 2; ++r)
        #pragma unroll
        for (int h = 0; h < 2; ++h)
            P[r][h] = p4[r * 128 + h * 64 + lane];

    const float fw  = (float)(*img_w_p);
    const float fh  = (float)(*img_h_p);
    const float sxs = (float)AW_ / fw;
    const float sys = (float)AH_ / fh;

    // ---- box geometry, once per wave (boxes lane and lane+64) ----
    bool  act_any[2];
    int   actb[2];
    int   gx1[2], gx2[2];
    float gx1m[2], gx2m[2];
    float rv0[2], rv1[2];
    #pragma unroll
    for (int k = 0; k < 2; ++k) {
        const int n = lane + 64 * k;
        const float* bp = bboxs + ((size_t)b * N_ + n) * 5;
        const float c0 = bp[0], c1 = bp[1], c2 = bp[2], c3 = bp[3], lab = bp[4];
        const bool valid = (lab != -1.0f) && (c0 <= fw) && (c1 <= fh)
                                          && (c2 <= fw) && (c3 <= fh);
        const float bx1 = c0 * sxs, by1 = c1 * sys;
        const float bx2 = c2 * sxs, by2 = c3 * sys;
        const float fx1 = floorf(bx1), fy1 = floorf(by1);
        const float x1m = fx1 + 1.0f - bx1;
        const float y1m = fy1 + 1.0f - by1;
        const float x2m = bx2 - floorf(bx2);
        const float y2m = by2 - floorf(by2);
        const int x1 = (int)fmaxf(fx1, 0.0f);
        const int y1 = (int)fmaxf(fy1, 0.0f);
        const int x2 = (int)fminf(ceilf(bx2) + 1.0f, (float)AW_);
        const int y2 = (int)fminf(ceilf(by2) + 1.0f, (float)AH_);
        gx1[k] = x1; gx2[k] = x2; gx1m[k] = x1m; gx2m[k] = x2m;
        int ab = 0;
        #pragma unroll
        for (int r = 0; r < 2; ++r) {
            const int y = y0 + r;
            const bool a = valid && (y >= y1) && (y < y2);
            ab |= a ? (1 << r) : 0;
            const float rw = ((y == y1)     ? y1m : 1.0f)
                           * ((y == y2 - 1) ? y2m : 1.0f);
            if (r == 0) rv0[k] = rw; else rv1[k] = rw;
        }
        actb[k]    = ab;
        act_any[k] = (ab != 0);
    }

    const unsigned long long ltm  = (1ull << lane) - 1ull;
    const unsigned long long bal0 = __ballot(act_any[0]);
    const unsigned long long bal1 = __ballot(act_any[1]);
    const bool have = (bal0 | bal1) != 0ull;

    float* m0 = s_mask[wid][0];
    float* m1 = s_mask[wid][1];
    float4* mrow4 = (float4*)m0;

    if (have) {
        const float4 z = make_float4(0.f, 0.f, 0.f, 0.f);
        #pragma unroll
        for (int q = 0; q < 4; ++q) mrow4[lane + 64 * q] = z;
        CFENCE();

        #pragma unroll
        for (int k = 0; k < 2; ++k) {
            const unsigned long long bal = (k == 0) ? bal0 : bal1;
            const int cnt = __popcll(bal);
            if (cnt == 0) continue;
            if (act_any[k]) {
                const int slot = __popcll(bal & ltm);
                s_geo[wid][slot] = make_float4(
                    __int_as_float(gx1[k] | (gx2[k] << 10) | (actb[k] << 20)),
                    gx1m[k], gx2m[k], 0.0f);
                s_rv[wid][slot] = make_float2(rv0[k], rv1[k]);
            }
            CFENCE();   // compaction writes precede list reads (in-order DS)

            float4 g_cur = s_geo[wid][0];
            float2 v_cur = s_rv[wid][0];
            for (int j = 0; j < cnt; ++j) {
                const float4 g = g_cur;
                const float2 v = v_cur;
                if (j + 1 < cnt) {
                    g_cur = s_geo[wid][j + 1];
                    v_cur = s_rv[wid][j + 1];
                }
                // scalar span bounds: SALU loop control
                const int px = __builtin_amdgcn_readfirstlane(__float_as_int(g.x));
                const int e1 = px & 1023;
                const int e2 = (px >> 10) & 1023;
                const int ab = px >> 20;
                for (int x = e1 + lane; x < e2; x += 64) {
                    const float edge = ((x == e1)     ? g.y : 1.0f)
                                     * ((x == e2 - 1) ? g.z : 1.0f);
                    if (ab & 1) m0[x] = v.x * edge;
                    if (ab & 2) m1[x] = v.y * edge;
                }
            }
            CFENCE();   // raster reads precede next chunk's compaction
        }
    }

    // ---- BCE in log2 domain (p in [1e-4,1-1e-4]: no clamps) ----
    float acc = 0.0f;
    #pragma unroll
    for (int r = 0; r < 2; ++r) {
        #pragma unroll
        for (int h = 0; h < 2; ++h) {
            const float4 p = P[r][h];
            float4 m = make_float4(0.f, 0.f, 0.f, 0.f);
            if (have) m = mrow4[r * 128 + h * 64 + lane];
            const float pv[4] = {p.x, p.y, p.z, p.w};
            const float mv[4] = {m.x, m.y, m.z, m.w};
            const bool nz = (m.x != 0.f) | (m.y != 0.f)
                          | (m.z != 0.f) | (m.w != 0.f);
            if (__any(nz)) {
                #pragma unroll
                for (int j = 0; j < 4; ++j) {
                    const float lp = __log2f(pv[j]);
                    const float l1 = __log2f(1.0f - pv[j]);
                    acc += l1 + mv[j] * (lp - l1);
                }
            } else {
                #pragma unroll
                for (int j = 0; j < 4; ++j)
                    acc += __log2f(1.0f - pv[j]);
            }
        }
    }

    // ---- wave reduce -> block partial -> last-block finalize ----
    #pragma unroll
    for (int off = 32; off; off >>= 1) acc += __shfl_down(acc, off, 64);
    if (lane == 0) s_bsum[wid] = acc;
    __syncthreads();
    if (t == 0) {
        block_sums[blockIdx.x] = s_bsum[0] + s_bsum[1];
        __threadfence();                       // release partials
        const unsigned old = atomicAdd(counter, 1u);
        s_last = (old == (unsigned)(gridDim.x - 1)) ? 1 : 0;
    }
    __syncthreads();

    if (s_last) {
        __threadfence();                       // acquire all partials
        // 128 threads: 4 workers per image
        const int bb = t >> 2;                 // image 0..31
        const int j  = t & 3;
        float s = 0.0f;
        #pragma unroll
        for (int k = 0; k < 32; ++k)
            s += block_sums[bb * 128 + j * 32 + k];

        int av = 0;
        const float* bp = bboxs + ((size_t)bb * N_ + j * 32) * 5;
        for (int n = 0; n < 32; ++n) {
            const float c0 = bp[n * 5 + 0];
            const float c1 = bp[n * 5 + 1];
            const float c2 = bp[n * 5 + 2];
            const float c3 = bp[n * 5 + 3];
            const float lb = bp[n * 5 + 4];
            av |= ((lb != -1.0f) && (c0 <= fw) && (c1 <= fh)
                                 && (c2 <= fw) && (c3 <= fh)) ? 1 : 0;
        }

        __shared__ float s_s[128];
        __shared__ int   s_a[128];
        __shared__ float s_loss[B_];
        s_s[t] = s;
        s_a[t] = av;
        __syncthreads();
        if (t < B_) {
            const float sum = s_s[4*t] + s_s[4*t+1] + s_s[4*t+2] + s_s[4*t+3];
            const int  anyv = s_a[4*t] | s_a[4*t+1] | s_a[4*t+2] | s_a[4*t+3];
            // log2-domain sum -> natural via LN2; fixed order => deterministic
            s_loss[t] = anyv ? (-sum * (LN2 / (float)(AH_ * AW_))) : 0.0f;
        }
        __syncthreads();
        if (t == 0) {
            float total = 0.0f;
            #pragma unroll
            for (int k = 0; k < B_; ++k) total += s_loss[k];
            out[0] = total * (1.0f / (float)B_);
        }
    }
}

extern "C" void kernel_launch(void* const* d_in, const int* in_sizes, int n_in,
                              void* d_out, int out_size, void* d_ws, size_t ws_size,
                              hipStream_t stream)
{
    const float* att   = (const float*)d_in[0];   // (32,1,512,512) f32
    const float* bboxs = (const float*)d_in[1];   // (32,128,5) f32
    const int*   img_h = (const int*)d_in[2];     // scalar
    const int*   img_w = (const int*)d_in[3];     // scalar
    float* out = (float*)d_out;

    float*    block_sums = (float*)d_ws;                  // 4096 floats
    unsigned* counter    = (unsigned*)(block_sums + 4096);

    hipMemsetAsync(counter, 0, sizeof(unsigned), stream); // capture-legal node
    row_bce_kernel<<<B_ * AH_ / 4, 128, 0, stream>>>(
        att, bboxs, img_h, img_w, block_sums, counter, out);
}

// Round 14
// 27.707 us; speedup vs baseline: 3.4695x; 3.4695x over previous
//
#include <hip/hip_runtime.h>
#include <hip/hip_bf16.h>

#define B_   32
#define N_   128
#define AH_  512
#define AW_  512
#define LCAP 64    // per-chunk list capacity (one 64-box ballot chunk)
#define LN2  0.69314718055994530942f

// compiler-only reordering fence; one wave's DS ops execute in issue order
#define CFENCE() asm volatile("" ::: "memory")

// ---------------------------------------------------------------------------
// R14 = R6 body (best, 29.4us; att-loads-FIRST is load-bearing: every
// bbox-first variant cost +6us) with issue-thinning only:
//  - BCE ungated: always 2 logs+fma per pixel (the __any gates' 16
//    ballot+branch per wave cost more issue than the skipped logs, which
//    total ~0.4us chip-wide)
//  - branchless span loop: scalar trip count, lanes clamp x to e2-1
//    (clamped lanes rewrite the edge value: same addr+value, harmless)
//  - log2-domain accumulation, one x ln2 per wave before the reduce
// Tail identical to R6 (1-block final_kernel; R13 proved single-counter
// last-block fusion serializes the grid).
// ---------------------------------------------------------------------------
__global__ __launch_bounds__(128) void row_bce_kernel(
    const float* __restrict__ att,
    const float* __restrict__ bboxs,
    const int*   __restrict__ img_h_p,
    const int*   __restrict__ img_w_p,
    float*       __restrict__ wave_sums)
{
    const int t    = threadIdx.x;
    const int lane = t & 63;
    const int wid  = t >> 6;                    // 0..1
    const int task = (blockIdx.x << 1) | wid;   // 0..8191
    const int b    = task >> 8;                 // 256 tasks per image
    const int y0   = (task & 255) << 1;         // rows y0, y0+1

    __shared__ float4 s_geo[2][LCAP];           // {pack(x1,x2,ab), x1m, x2m, -}
    __shared__ float2 s_rv [2][LCAP];           // {rowv0, rowv1}
    __shared__ float  s_mask[2][2][AW_];        // [wid][row][x]

    // ---- att loads FIRST (proven ordering) ----
    const float4* p4 = (const float4*)(att + ((size_t)b * AH_ + y0) * AW_);
    float4 P[2][2];
    #pragma unroll
    for (int r = 0; r < 2; ++r)
        #pragma unroll
        for (int h = 0; h < 2; ++h)
            P[r][h] = p4[r * 128 + h * 64 + lane];

    const float fw  = (float)(*img_w_p);
    const float fh  = (float)(*img_h_p);
    const float sxs = (float)AW_ / fw;
    const float sys = (float)AH_ / fh;

    // ---- box geometry, once per wave (boxes lane and lane+64) ----
    bool  act_any[2];
    int   actb[2];
    int   gx1[2], gx2[2];
    float gx1m[2], gx2m[2];
    float rv0[2], rv1[2];
    #pragma unroll
    for (int k = 0; k < 2; ++k) {
        const int n = lane + 64 * k;
        const float* bp = bboxs + ((size_t)b * N_ + n) * 5;
        const float c0 = bp[0], c1 = bp[1], c2 = bp[2], c3 = bp[3], lab = bp[4];
        const bool valid = (lab != -1.0f) && (c0 <= fw) && (c1 <= fh)
                                          && (c2 <= fw) && (c3 <= fh);
        const float bx1 = c0 * sxs, by1 = c1 * sys;
        const float bx2 = c2 * sxs, by2 = c3 * sys;
        const float fx1 = floorf(bx1), fy1 = floorf(by1);
        const float x1m = fx1 + 1.0f - bx1;
        const float y1m = fy1 + 1.0f - by1;
        const float x2m = bx2 - floorf(bx2);
        const float y2m = by2 - floorf(by2);
        const int x1 = (int)fmaxf(fx1, 0.0f);
        const int y1 = (int)fmaxf(fy1, 0.0f);
        const int x2 = (int)fminf(ceilf(bx2) + 1.0f, (float)AW_);
        const int y2 = (int)fminf(ceilf(by2) + 1.0f, (float)AH_);
        gx1[k] = x1; gx2[k] = x2; gx1m[k] = x1m; gx2m[k] = x2m;
        int ab = 0;
        #pragma unroll
        for (int r = 0; r < 2; ++r) {
            const int y = y0 + r;
            const bool a = valid && (y >= y1) && (y < y2);
            ab |= a ? (1 << r) : 0;
            const float rw = ((y == y1)     ? y1m : 1.0f)
                           * ((y == y2 - 1) ? y2m : 1.0f);
            if (r == 0) rv0[k] = rw; else rv1[k] = rw;
        }
        actb[k]    = ab;
        act_any[k] = (ab != 0) && (x1 < x2);
    }

    const unsigned long long ltm  = (1ull << lane) - 1ull;
    const unsigned long long bal0 = __ballot(act_any[0]);
    const unsigned long long bal1 = __ballot(act_any[1]);
    const bool have = (bal0 | bal1) != 0ull;

    float* m0 = s_mask[wid][0];
    float* m1 = s_mask[wid][1];
    float4* mrow4 = (float4*)m0;

    if (have) {
        // zero both mask rows: 4x ds_write_b128 per lane
        const float4 z = make_float4(0.f, 0.f, 0.f, 0.f);
        #pragma unroll
        for (int q = 0; q < 4; ++q) mrow4[lane + 64 * q] = z;
        CFENCE();

        // ---- two 64-box chunks in index order; list buffer reused ----
        #pragma unroll
        for (int k = 0; k < 2; ++k) {
            const unsigned long long bal = (k == 0) ? bal0 : bal1;
            const int cnt = __popcll(bal);
            if (cnt == 0) continue;
            if (act_any[k]) {
                const int slot = __popcll(bal & ltm);
                s_geo[wid][slot] = make_float4(
                    __int_as_float(gx1[k] | (gx2[k] << 10) | (actb[k] << 20)),
                    gx1m[k], gx2m[k], 0.0f);
                s_rv[wid][slot] = make_float2(rv0[k], rv1[k]);
            }
            CFENCE();   // compaction writes precede list reads (in-order DS)

            // raster with 1-deep prefetch; branchless uniform span loop
            float4 g_cur = s_geo[wid][0];
            float2 v_cur = s_rv[wid][0];
            for (int j = 0; j < cnt; ++j) {
                const float4 g = g_cur;
                const float2 v = v_cur;
                if (j + 1 < cnt) {
                    g_cur = s_geo[wid][j + 1];
                    v_cur = s_rv[wid][j + 1];
                }
                const int px = __builtin_amdgcn_readfirstlane(__float_as_int(g.x));
                const int e1 = px & 1023;
                const int e2 = (px >> 10) & 1023;
                const int ab = px >> 20;
                const int iters = (e2 - e1 + 63) >> 6;       // scalar trip count
                for (int q = 0; q < iters; ++q) {
                    const int xr = e1 + (q << 6) + lane;
                    const int x  = (xr < e2) ? xr : (e2 - 1); // clamp: rewrite edge
                    const float edge = ((x == e1)     ? g.y : 1.0f)
                                     * ((x == e2 - 1) ? g.z : 1.0f);
                    if (ab & 1) m0[x] = v.x * edge;
                    if (ab & 2) m1[x] = v.y * edge;
                }
            }
            CFENCE();   // raster reads precede next chunk's compaction
        }
    }

    // ---- BCE (ungated, log2 domain; p in [1e-4,1-1e-4]: no clamps) ----
    float acc = 0.0f;
    #pragma unroll
    for (int r = 0; r < 2; ++r) {
        #pragma unroll
        for (int h = 0; h < 2; ++h) {
            const float4 p = P[r][h];
            float4 m = make_float4(0.f, 0.f, 0.f, 0.f);
            if (have) m = mrow4[r * 128 + h * 64 + lane];
            const float pv[4] = {p.x, p.y, p.z, p.w};
            const float mv[4] = {m.x, m.y, m.z, m.w};
            #pragma unroll
            for (int j = 0; j < 4; ++j) {
                const float lp = __log2f(pv[j]);
                const float l1 = __log2f(1.0f - pv[j]);
                acc += l1 + mv[j] * (lp - l1);
            }
        }
    }
    acc *= LN2;   // one natural-log scale per wave

    // ---- wave reduction -> per-task partial ----
    #pragma unroll
    for (int off = 32; off; off >>= 1) acc += __shfl_down(acc, off, 64);
    if (lane == 0) wave_sums[task] = acc;
}

// ---------------------------------------------------------------------------
// Fused tail: per-image reduce of 256 task partials + any_valid gate +
// batch mean. One block, 1024 threads (32 workers per image). (R6 verbatim.)
// ---------------------------------------------------------------------------
__global__ __launch_bounds__(1024) void final_kernel(
    const float* __restrict__ bboxs,
    const int*   __restrict__ img_h_p,
    const int*   __restrict__ img_w_p,
    const float* __restrict__ wave_sums,
    float*       __restrict__ out)
{
    const int t = threadIdx.x;
    const int b = t >> 5;        // image 0..31
    const int j = t & 31;        // worker within image

    __shared__ float s_sum[1024];
    __shared__ int   s_any[1024];
    __shared__ float s_loss[B_];

    float s = 0.0f;
    #pragma unroll
    for (int k = 0; k < 8; ++k) s += wave_sums[b * 256 + j + 32 * k];
    s_sum[t] = s;

    const float fw = (float)(*img_w_p);
    const float fh = (float)(*img_h_p);
    int av = 0;
    const float* bp = bboxs + (size_t)b * N_ * 5;
    #pragma unroll
    for (int n = j * 4; n < j * 4 + 4; ++n) {
        const float c0 = bp[n * 5 + 0];
        const float c1 = bp[n * 5 + 1];
        const float c2 = bp[n * 5 + 2];
        const float c3 = bp[n * 5 + 3];
        const float lab = bp[n * 5 + 4];
        av |= ((lab != -1.0f) && (c0 <= fw) && (c1 <= fh)
                              && (c2 <= fw) && (c3 <= fh)) ? 1 : 0;
    }
    s_any[t] = av;
    __syncthreads();

    if (j == 0) {
        float sum = 0.0f;
        int anyv = 0;
        for (int k = 0; k < 32; ++k) {
            sum  += s_sum[b * 32 + k];
            anyv |= s_any[b * 32 + k];
        }
        s_loss[b] = anyv ? (-sum * (1.0f / (float)(AH_ * AW_))) : 0.0f;
    }
    __syncthreads();

    if (t == 0) {
        float total = 0.0f;
        for (int k = 0; k < B_; ++k) total += s_loss[k];
        out[0] = total * (1.0f / (float)B_);
    }
}

extern "C" void kernel_launch(void* const* d_in, const int* in_sizes, int n_in,
                              void* d_out, int out_size, void* d_ws, size_t ws_size,
                              hipStream_t stream)
{
    const float* att   = (const float*)d_in[0];   // (32,1,512,512) f32
    const float* bboxs = (const float*)d_in[1];   // (32,128,5) f32
    const int*   img_h = (const int*)d_in[2];     // scalar
    const int*   img_w = (const int*)d_in[3];     // scalar
    float* out = (float*)d_out;
    float* wave_sums = (float*)d_ws;              // 8192 floats (32 KB)

    row_bce_kernel<<<B_ * AH_ / 4, 128, 0, stream>>>(att, bboxs, img_h, img_w, wave_sums);
    final_kernel<<<1, 1024, 0, stream>>>(bboxs, img_h, img_w, wave_sums, out);
}